// Round 8
// baseline (371.283 us; speedup 1.0000x reference)
//
#include <hip/hip_runtime.h>
#include <cfloat>
#include <math.h>

// Exact-replication KNN (k=10, +self) + rank-column gather max-pool.
// NUMERICS FROZEN (R3 pass, absmax 0.0): fp32 chains
//   sq  = fma(z,z, fma(y,y, rn(x*x)))
//   dot = fma(z,z', fma(y,y', rn(x*x')))
//   d   = fma(dot, -2, rn(sq_i+sq_j))    [== rn(sum - rn(2*dot)), 2*dot exact]
// Selection order = jax top_k = ascending lexicographic (d, orig_idx).
//
// Round 8: spatial pruning. Prepass sorts points by 16^3 Morton cells into
// d_ws as float4(x,y,z,orig_idx); main kernel scans the query's own 512-pt
// tile first (worst pre-tightened by a 16-candidate group max — a sound
// upper bound on the final 11th distance), then LB-skips the other 31 tiles
// via per-tile AABBs with a 1e-3 margin (>> all fp32 chain error bounds).
// Scan order is free because the insert comparator is fully lexicographic
// (d, orig_idx) — bitwise ties resolve exactly as jax top_k regardless of
// the nondeterministic scatter order. Self: d==0.0 by identical chains,
// dropped positionally (rank 0 of the lex order, as in the reference).

#define N_PTS    16384
#define C_FEAT   64
#define KK       11
#define NCELLS   4096                 // 16^3 Morton cells
#define TILE     512                  // sorted points per tile
#define NTILES   (N_PTS / TILE)       // 32
#define BPT      (TILE / 64)          // batches per tile = 8
#define WQ       4
#define NWAVES   4
#define NTHREADS (NWAVES * 64)
#define QPB      (NWAVES * WQ)        // 16 queries per block

// d_ws layout (bytes)
#define WS_CAND  0                          // float4[2][N_PTS]   512 KB
#define WS_HIST  (WS_CAND + 2*N_PTS*16)     // int[2][NCELLS]      32 KB
#define WS_PTR   (WS_HIST + 2*NCELLS*4)     // int[2][NCELLS]      32 KB
#define WS_AABB  (WS_PTR  + 2*NCELLS*4)     // float[2][NTILES][6]

__device__ __forceinline__ int cell_of(float x, float y, float z) {
    int cx = (int)floorf((x + 4.5f) * (16.0f / 9.0f));
    int cy = (int)floorf((y + 4.5f) * (16.0f / 9.0f));
    int cz = (int)floorf((z + 4.5f) * (16.0f / 9.0f));
    cx = min(15, max(0, cx));
    cy = min(15, max(0, cy));
    cz = min(15, max(0, cz));
    int m = 0;
    #pragma unroll
    for (int b = 0; b < 4; ++b)
        m |= (((cx >> b) & 1) << (3 * b)) |
             (((cy >> b) & 1) << (3 * b + 1)) |
             (((cz >> b) & 1) << (3 * b + 2));
    return m;
}

__global__ void hist_kernel(const float* __restrict__ src_c,
                            const float* __restrict__ tgt_c,
                            int* __restrict__ hist) {
    const int i = blockIdx.x * blockDim.x + threadIdx.x;   // 0..32767
    const int inst = i >> 14, p = i & (N_PTS - 1);
    const float* c = (inst ? tgt_c : src_c) + (size_t)p * 3;
    atomicAdd(&hist[inst * NCELLS + cell_of(c[0], c[1], c[2])], 1);
}

__global__ void scan_kernel(const int* __restrict__ hist,
                            int* __restrict__ cellPtr) {
    __shared__ int sd[1024];
    const int inst = blockIdx.x, t = threadIdx.x;
    int v[4], s = 0;
    #pragma unroll
    for (int j = 0; j < 4; ++j) { v[j] = hist[inst * NCELLS + t * 4 + j]; s += v[j]; }
    sd[t] = s;
    __syncthreads();
    for (int off = 1; off < 1024; off <<= 1) {
        int x = (t >= off) ? sd[t - off] : 0;
        __syncthreads();
        sd[t] += x;
        __syncthreads();
    }
    int excl = sd[t] - s;
    #pragma unroll
    for (int j = 0; j < 4; ++j) { cellPtr[inst * NCELLS + t * 4 + j] = excl; excl += v[j]; }
}

__global__ void scatter_kernel(const float* __restrict__ src_c,
                               const float* __restrict__ tgt_c,
                               int* __restrict__ cellPtr,
                               float4* __restrict__ cand) {
    const int i = blockIdx.x * blockDim.x + threadIdx.x;
    const int inst = i >> 14, p = i & (N_PTS - 1);
    const float* c = (inst ? tgt_c : src_c) + (size_t)p * 3;
    const float x = c[0], y = c[1], z = c[2];
    const int dst = atomicAdd(&cellPtr[inst * NCELLS + cell_of(x, y, z)], 1);
    cand[inst * N_PTS + dst] = make_float4(x, y, z, __int_as_float(p));
}

__global__ void aabb_kernel(const float4* __restrict__ cand,
                            float* __restrict__ aabb) {
    const int it = blockIdx.x;                 // inst*NTILES + tile
    const int base = (it >> 5) * N_PTS + (it & 31) * TILE;
    const int t = threadIdx.x;                 // 256 threads, 2 pts each
    float4 a = cand[base + 2 * t], b = cand[base + 2 * t + 1];
    float mnx = fminf(a.x, b.x), mny = fminf(a.y, b.y), mnz = fminf(a.z, b.z);
    float mxx = fmaxf(a.x, b.x), mxy = fmaxf(a.y, b.y), mxz = fmaxf(a.z, b.z);
    #pragma unroll
    for (int off = 1; off < 64; off <<= 1) {
        mnx = fminf(mnx, __shfl_xor(mnx, off));
        mny = fminf(mny, __shfl_xor(mny, off));
        mnz = fminf(mnz, __shfl_xor(mnz, off));
        mxx = fmaxf(mxx, __shfl_xor(mxx, off));
        mxy = fmaxf(mxy, __shfl_xor(mxy, off));
        mxz = fmaxf(mxz, __shfl_xor(mxz, off));
    }
    __shared__ float red[4][6];
    if ((t & 63) == 0) {
        const int w = t >> 6;
        red[w][0] = mnx; red[w][1] = mny; red[w][2] = mnz;
        red[w][3] = mxx; red[w][4] = mxy; red[w][5] = mxz;
    }
    __syncthreads();
    if (t == 0) {
        float o[6];
        #pragma unroll
        for (int j = 0; j < 3; ++j)
            o[j] = fminf(fminf(red[0][j], red[1][j]), fminf(red[2][j], red[3][j]));
        #pragma unroll
        for (int j = 3; j < 6; ++j)
            o[j] = fmaxf(fmaxf(red[0][j], red[1][j]), fmaxf(red[2][j], red[3][j]));
        #pragma unroll
        for (int j = 0; j < 6; ++j) aabb[it * 6 + j] = o[j];
    }
}

__global__ __launch_bounds__(NTHREADS) void knn_pool_kernel(
    const float* __restrict__ src_f, const float* __restrict__ tgt_f,
    const float4* __restrict__ cand, const float* __restrict__ aabb,
    float* __restrict__ out)
{
    const int inst = blockIdx.x & 1;
    const float* __restrict__ feats = inst ? tgt_f : src_f;
    float* __restrict__ outb = out + (size_t)inst * N_PTS * (2 * C_FEAT);
    const float4* __restrict__ cd = cand + inst * N_PTS;

    const int tid = threadIdx.x, wave = tid >> 6, lane = tid & 63;
    const int lq = lane >> 4, lrank = lane & 15;
    const bool inlist = (lrank < KK);
    const int upaddr = ((lane + 63) & 63) << 2;   // ds_bpermute: lane-1

    __shared__ float sab[NTILES * 6];
    if (tid < NTILES * 6) sab[tid] = aabb[inst * NTILES * 6 + tid];
    __syncthreads();

    const int q0 = (blockIdx.x >> 1) * QPB + wave * WQ;   // sorted row
    float qx[WQ], qy[WQ], qz[WQ], qsq[WQ];
    int qor[WQ]; bool ingrp[WQ]; float worst[WQ];
    float wqmnx = FLT_MAX, wqmny = FLT_MAX, wqmnz = FLT_MAX;
    float wqmxx = -FLT_MAX, wqmxy = -FLT_MAX, wqmxz = -FLT_MAX;
    #pragma unroll
    for (int q = 0; q < WQ; ++q) {
        const float4 c = cd[q0 + q];
        qx[q] = c.x; qy[q] = c.y; qz[q] = c.z;
        qor[q] = __float_as_int(c.w);
        qsq[q] = __fmaf_rn(c.z, c.z, __fmaf_rn(c.y, c.y, __fmul_rn(c.x, c.x)));
        ingrp[q] = inlist && (lq == q);
        worst[q] = FLT_MAX;
        wqmnx = fminf(wqmnx, c.x); wqmxx = fmaxf(wqmxx, c.x);
        wqmny = fminf(wqmny, c.y); wqmxy = fmaxf(wqmxy, c.y);
        wqmnz = fminf(wqmnz, c.z); wqmxz = fmaxf(wqmxz, c.z);
    }

    float ld = FLT_MAX;   // lane-distributed sorted list (lex (d, orig_idx))
    int   li = 0x7fffffff;

    const int ownt   = q0 >> 9;          // tile containing the queries
    const int startb = (q0 & 511) >> 6;  // batch (within tile) containing q0

    for (int tt = 0; tt < NTILES; ++tt) {
        const bool first = (tt == 0);
        int t;
        if (first) t = ownt;
        else {
            t = (tt <= ownt) ? (tt - 1) : tt;  // all tiles except ownt
            // sound skip: lb - margin > max(worst) => no candidate can enter
            const float dx = fmaxf(0.0f, fmaxf(sab[t*6+0] - wqmxx, wqmnx - sab[t*6+3]));
            const float dy = fmaxf(0.0f, fmaxf(sab[t*6+1] - wqmxy, wqmny - sab[t*6+4]));
            const float dz = fmaxf(0.0f, fmaxf(sab[t*6+2] - wqmxz, wqmnz - sab[t*6+5]));
            float lb = dx * dx;
            lb = fmaf(dy, dy, lb);
            lb = fmaf(dz, dz, lb);
            const float wmax = fmaxf(fmaxf(worst[0], worst[1]),
                                     fmaxf(worst[2], worst[3]));
            if (lb - 1e-3f > wmax) continue;
        }

        for (int bi = 0; bi < BPT; ++bi) {
            const int b = first ? ((startb + bi) & (BPT - 1)) : bi;
            const float4 c = cd[t * TILE + b * 64 + lane];
            const float cx = c.x, cy = c.y, cz = c.z;
            const int corig = __float_as_int(c.w);
            const float csq = __fmaf_rn(cz, cz,
                              __fmaf_rn(cy, cy, __fmul_rn(cx, cx)));

            #pragma unroll
            for (int q = 0; q < WQ; ++q) {
                float dot = __fmul_rn(cx, qx[q]);
                dot = __fmaf_rn(cy, qy[q], dot);
                dot = __fmaf_rn(cz, qz[q], dot);
                const float sum = __fadd_rn(qsq[q], csq);
                const float d = __fmaf_rn(dot, -2.0f, sum);

                if (first && bi == 0) {
                    // worst_init = max d over 16 spatially-near candidates
                    // >= their 11th >= final 11th  (sound upper bound)
                    float t16 = d;
                    #pragma unroll
                    for (int off = 1; off < 16; off <<= 1)
                        t16 = fmaxf(t16, __shfl_xor(t16, off));
                    worst[q] = __int_as_float(__builtin_amdgcn_readlane(
                        __float_as_int(t16), q * 16));
                }

                unsigned long long m = __ballot(d <= worst[q]);
                while (m) {
                    const int sl = (int)__builtin_ctzll(m);
                    m &= m - 1;
                    const float nd = __int_as_float(__builtin_amdgcn_readlane(
                        __float_as_int(d), sl));
                    if (nd <= worst[q]) {      // recheck (worst tightens)
                        const int norig = __builtin_amdgcn_readlane(corig, sl);
                        const float pld = __int_as_float(
                            __builtin_amdgcn_ds_bpermute(upaddr, __float_as_int(ld)));
                        const int pli =
                            __builtin_amdgcn_ds_bpermute(upaddr, li);
                        // lex comparator (d, orig): shift entries > new
                        const bool gt = (ld > nd) || (ld == nd && li > norig);
                        if (ingrp[q] && gt) {
                            const bool pgt = (pld > nd) || (pld == nd && pli > norig);
                            const bool fst = (lrank == 0) || (!pgt);
                            ld = fst ? nd : pld;
                            li = fst ? norig : pli;
                        }
                        worst[q] = fminf(worst[q],
                            __int_as_float(__builtin_amdgcn_readlane(
                                __float_as_int(ld), q * 16 + (KK - 1))));
                    }
                }
            }
        }
    }

    // Rank 0 (lex-smallest: self or -1ulp near-twin) dropped positionally.
    // Ranks 1..10 -> feature columns 0..9. li holds ORIGINAL indices.
    float fv = -FLT_MAX;
    if (inlist && lrank >= 1)
        fv = feats[(size_t)li * C_FEAT + (lrank - 1)];
    #pragma unroll
    for (int off = 1; off < 16; off <<= 1)
        fv = fmaxf(fv, __shfl_xor(fv, off));

    #pragma unroll
    for (int q = 0; q < WQ; ++q) {
        const float M   = __shfl(fv, q * 16);
        const int   row = qor[q];
        const float v   = feats[(size_t)row * C_FEAT + lane];
        outb[(size_t)row * (2 * C_FEAT) + lane]          = v;
        outb[(size_t)row * (2 * C_FEAT) + C_FEAT + lane] = M - v;
    }
}

extern "C" void kernel_launch(void* const* d_in, const int* in_sizes, int n_in,
                              void* d_out, int out_size, void* d_ws, size_t ws_size,
                              hipStream_t stream) {
    const float* src_f = (const float*)d_in[0];
    const float* tgt_f = (const float*)d_in[1];
    const float* src_c = (const float*)d_in[2];
    const float* tgt_c = (const float*)d_in[3];
    float* out = (float*)d_out;

    char* ws = (char*)d_ws;
    float4* cand   = (float4*)(ws + WS_CAND);
    int*    hist   = (int*)   (ws + WS_HIST);
    int*    cptr   = (int*)   (ws + WS_PTR);
    float*  aabb   = (float*) (ws + WS_AABB);

    hipMemsetAsync(hist, 0, 2 * NCELLS * sizeof(int), stream);
    hipLaunchKernelGGL(hist_kernel, dim3(2 * N_PTS / 256), dim3(256), 0, stream,
                       src_c, tgt_c, hist);
    hipLaunchKernelGGL(scan_kernel, dim3(2), dim3(1024), 0, stream, hist, cptr);
    hipLaunchKernelGGL(scatter_kernel, dim3(2 * N_PTS / 256), dim3(256), 0, stream,
                       src_c, tgt_c, cptr, cand);
    hipLaunchKernelGGL(aabb_kernel, dim3(2 * NTILES), dim3(256), 0, stream,
                       cand, aabb);
    hipLaunchKernelGGL(knn_pool_kernel, dim3(2 * (N_PTS / QPB)), dim3(NTHREADS),
                       0, stream, src_f, tgt_f, cand, aabb, out);
}

// Round 9
// 239.934 us; speedup vs baseline: 1.5474x; 1.5474x over previous
//
#include <hip/hip_runtime.h>
#include <cfloat>
#include <math.h>

// Exact-replication KNN (k=10, +self) + rank-column gather max-pool.
// NUMERICS FROZEN (R3 pass, absmax 0.0): fp32 chains
//   sq  = fma(z,z, fma(y,y, rn(x*x)))
//   dot = fma(z,z', fma(y,y', rn(x*x')))
//   d   = fma(dot, -2, rn(sq_i+sq_j))    [== rn(sum - rn(2*dot)), 2*dot exact]
// Selection order = jax top_k = ascending lexicographic (d, orig_idx) —
// proven order-independent in R8 (absmax 0.0 with nondeterministic scatter).
//
// Round 9: R8 pruning kept, its two failure modes fixed:
//  - 128 tiles x 128 pts (4x tighter AABBs) + near->far zigzag survivor
//    list per wave (parallel ballot build) => fewer candidates in the tail.
//  - ping-pong register prefetch (2 float4 batches in flight) over the
//    survivor list => tail waves stay latency-hidden even at low occupancy
//    (R8's collapse: 28% occupancy + dependent global loads = 33% VALUBusy).

#define N_PTS    16384
#define C_FEAT   64
#define KK       11
#define NCELLS   4096                 // 16^3 Morton cells
#define TILE     128                  // sorted points per tile
#define NTILES   (N_PTS / TILE)       // 128
#define WQ       4
#define NWAVES   4
#define NTHREADS (NWAVES * 64)
#define QPB      (NWAVES * WQ)        // 16 queries per block

// d_ws layout (bytes)
#define WS_CAND  0                          // float4[2][N_PTS]   512 KB
#define WS_HIST  (WS_CAND + 2*N_PTS*16)     // int[2][NCELLS]      32 KB
#define WS_PTR   (WS_HIST + 2*NCELLS*4)     // int[2][NCELLS]      32 KB
#define WS_AABB  (WS_PTR  + 2*NCELLS*4)     // float[2][NTILES][6]

__device__ __forceinline__ int cell_of(float x, float y, float z) {
    int cx = (int)floorf((x + 4.5f) * (16.0f / 9.0f));
    int cy = (int)floorf((y + 4.5f) * (16.0f / 9.0f));
    int cz = (int)floorf((z + 4.5f) * (16.0f / 9.0f));
    cx = min(15, max(0, cx));
    cy = min(15, max(0, cy));
    cz = min(15, max(0, cz));
    int m = 0;
    #pragma unroll
    for (int b = 0; b < 4; ++b)
        m |= (((cx >> b) & 1) << (3 * b)) |
             (((cy >> b) & 1) << (3 * b + 1)) |
             (((cz >> b) & 1) << (3 * b + 2));
    return m;
}

__global__ void hist_kernel(const float* __restrict__ src_c,
                            const float* __restrict__ tgt_c,
                            int* __restrict__ hist) {
    const int i = blockIdx.x * blockDim.x + threadIdx.x;
    const int inst = i >> 14, p = i & (N_PTS - 1);
    const float* c = (inst ? tgt_c : src_c) + (size_t)p * 3;
    atomicAdd(&hist[inst * NCELLS + cell_of(c[0], c[1], c[2])], 1);
}

__global__ void scan_kernel(const int* __restrict__ hist,
                            int* __restrict__ cellPtr) {
    __shared__ int sd[1024];
    const int inst = blockIdx.x, t = threadIdx.x;
    int v[4], s = 0;
    #pragma unroll
    for (int j = 0; j < 4; ++j) { v[j] = hist[inst * NCELLS + t * 4 + j]; s += v[j]; }
    sd[t] = s;
    __syncthreads();
    for (int off = 1; off < 1024; off <<= 1) {
        int x = (t >= off) ? sd[t - off] : 0;
        __syncthreads();
        sd[t] += x;
        __syncthreads();
    }
    int excl = sd[t] - s;
    #pragma unroll
    for (int j = 0; j < 4; ++j) { cellPtr[inst * NCELLS + t * 4 + j] = excl; excl += v[j]; }
}

__global__ void scatter_kernel(const float* __restrict__ src_c,
                               const float* __restrict__ tgt_c,
                               int* __restrict__ cellPtr,
                               float4* __restrict__ cand) {
    const int i = blockIdx.x * blockDim.x + threadIdx.x;
    const int inst = i >> 14, p = i & (N_PTS - 1);
    const float* c = (inst ? tgt_c : src_c) + (size_t)p * 3;
    const float x = c[0], y = c[1], z = c[2];
    const int dst = atomicAdd(&cellPtr[inst * NCELLS + cell_of(x, y, z)], 1);
    cand[inst * N_PTS + dst] = make_float4(x, y, z, __int_as_float(p));
}

__global__ void aabb_kernel(const float4* __restrict__ cand,
                            float* __restrict__ aabb) {
    const int it = blockIdx.x;                 // inst*NTILES + tile
    const int base = (it / NTILES) * N_PTS + (it % NTILES) * TILE;
    const int lane = threadIdx.x;              // 64 threads, 2 pts each
    float4 a = cand[base + lane], b = cand[base + 64 + lane];
    float mnx = fminf(a.x, b.x), mny = fminf(a.y, b.y), mnz = fminf(a.z, b.z);
    float mxx = fmaxf(a.x, b.x), mxy = fmaxf(a.y, b.y), mxz = fmaxf(a.z, b.z);
    #pragma unroll
    for (int off = 1; off < 64; off <<= 1) {
        mnx = fminf(mnx, __shfl_xor(mnx, off));
        mny = fminf(mny, __shfl_xor(mny, off));
        mnz = fminf(mnz, __shfl_xor(mnz, off));
        mxx = fmaxf(mxx, __shfl_xor(mxx, off));
        mxy = fmaxf(mxy, __shfl_xor(mxy, off));
        mxz = fmaxf(mxz, __shfl_xor(mxz, off));
    }
    if (lane == 0) {
        aabb[it * 6 + 0] = mnx; aabb[it * 6 + 1] = mny; aabb[it * 6 + 2] = mnz;
        aabb[it * 6 + 3] = mxx; aabb[it * 6 + 4] = mxy; aabb[it * 6 + 5] = mxz;
    }
}

// One 64-candidate batch against the wave's 4 queries. INIT: pre-tighten
// worst[q] from the 16 candidates in q's lane group (sound upper bound on
// the final 11th). Pop/insert path proven in R8 (absmax 0.0).
#define PROCESS_BATCH(C, INIT)                                              \
  {                                                                         \
    const float cx = (C).x, cy = (C).y, cz = (C).z;                         \
    const int corig = __float_as_int((C).w);                                \
    const float csq = __fmaf_rn(cz, cz, __fmaf_rn(cy, cy,                   \
                                __fmul_rn(cx, cx)));                        \
    _Pragma("unroll")                                                       \
    for (int q = 0; q < WQ; ++q) {                                          \
      float dot = __fmul_rn(cx, qx[q]);                                     \
      dot = __fmaf_rn(cy, qy[q], dot);                                      \
      dot = __fmaf_rn(cz, qz[q], dot);                                      \
      const float sum = __fadd_rn(qsq[q], csq);                             \
      const float d = __fmaf_rn(dot, -2.0f, sum);                           \
      if (INIT) {                                                           \
        float t16 = d;                                                      \
        _Pragma("unroll")                                                   \
        for (int off = 1; off < 16; off <<= 1)                              \
          t16 = fmaxf(t16, __shfl_xor(t16, off));                           \
        worst[q] = __int_as_float(__builtin_amdgcn_readlane(                \
            __float_as_int(t16), q * 16));                                  \
      }                                                                     \
      unsigned long long m = __ballot(d <= worst[q]);                       \
      while (m) {                                                           \
        const int sl = (int)__builtin_ctzll(m);                             \
        m &= m - 1;                                                         \
        const float nd = __int_as_float(__builtin_amdgcn_readlane(          \
            __float_as_int(d), sl));                                        \
        if (nd <= worst[q]) {                                               \
          const int norig = __builtin_amdgcn_readlane(corig, sl);           \
          const float pld = __int_as_float(                                 \
              __builtin_amdgcn_ds_bpermute(upaddr, __float_as_int(ld)));    \
          const int pli = __builtin_amdgcn_ds_bpermute(upaddr, li);         \
          const bool gt = (ld > nd) || (ld == nd && li > norig);            \
          if (ingrp[q] && gt) {                                             \
            const bool pgt = (pld > nd) || (pld == nd && pli > norig);      \
            const bool fst = (lrank == 0) || (!pgt);                        \
            ld = fst ? nd : pld;                                            \
            li = fst ? norig : pli;                                         \
          }                                                                 \
          worst[q] = fminf(worst[q],                                        \
              __int_as_float(__builtin_amdgcn_readlane(                     \
                  __float_as_int(ld), q * 16 + (KK - 1))));                 \
        }                                                                   \
      }                                                                     \
    }                                                                       \
  }

__global__ __launch_bounds__(NTHREADS) void knn_pool_kernel(
    const float* __restrict__ src_f, const float* __restrict__ tgt_f,
    const float4* __restrict__ cand, const float* __restrict__ aabb,
    float* __restrict__ out)
{
    const int inst = blockIdx.x & 1;
    const float* __restrict__ feats = inst ? tgt_f : src_f;
    float* __restrict__ outb = out + (size_t)inst * N_PTS * (2 * C_FEAT);
    const float4* __restrict__ cd = cand + inst * N_PTS;

    const int tid = threadIdx.x, wave = tid >> 6, lane = tid & 63;
    const int lq = lane >> 4, lrank = lane & 15;
    const bool inlist = (lrank < KK);
    const int upaddr = ((lane + 63) & 63) << 2;   // ds_bpermute: lane-1

    __shared__ float sab[NTILES * 6];                    // 3 KB
    __shared__ unsigned char slist[NWAVES][NTILES];      // survivor lists
    for (int i = tid; i < NTILES * 6; i += NTHREADS)
        sab[i] = aabb[inst * NTILES * 6 + i];
    __syncthreads();

    const int q0 = (blockIdx.x >> 1) * QPB + wave * WQ;  // sorted row
    float qx[WQ], qy[WQ], qz[WQ], qsq[WQ];
    int qor[WQ]; bool ingrp[WQ]; float worst[WQ];
    float wqmnx = FLT_MAX, wqmny = FLT_MAX, wqmnz = FLT_MAX;
    float wqmxx = -FLT_MAX, wqmxy = -FLT_MAX, wqmxz = -FLT_MAX;
    #pragma unroll
    for (int q = 0; q < WQ; ++q) {
        const float4 c = cd[q0 + q];
        qx[q] = c.x; qy[q] = c.y; qz[q] = c.z;
        qor[q] = __float_as_int(c.w);
        qsq[q] = __fmaf_rn(c.z, c.z, __fmaf_rn(c.y, c.y, __fmul_rn(c.x, c.x)));
        ingrp[q] = inlist && (lq == q);
        worst[q] = FLT_MAX;
        wqmnx = fminf(wqmnx, c.x); wqmxx = fmaxf(wqmxx, c.x);
        wqmny = fminf(wqmny, c.y); wqmxy = fmaxf(wqmxy, c.y);
        wqmnz = fminf(wqmnz, c.z); wqmxz = fmaxf(wqmxz, c.z);
    }

    float ld = FLT_MAX;   // lane-distributed sorted list (lex (d, orig_idx))
    int   li = 0x7fffffff;

    const int ownt = q0 / TILE;   // tile containing the queries

    // ---- own tile first: worst init on batch 0, tighten through batch 1 --
    {
        const float4 c0 = cd[ownt * TILE + lane];
        const float4 c1 = cd[ownt * TILE + 64 + lane];
        PROCESS_BATCH(c0, true);
        PROCESS_BATCH(c1, false);
    }
    const float wmax = fmaxf(fmaxf(worst[0], worst[1]),
                             fmaxf(worst[2], worst[3]));

    // ---- zigzag (near->far) survivor list, built in parallel ----
    // position p: o = p/2+1; p even -> ownt+o, p odd -> ownt-o.
    int nsurv = 0;
    #pragma unroll
    for (int g = 0; g < 4; ++g) {
        const int p = g * 64 + lane;
        const int o = (p >> 1) + 1;
        const int t = (p & 1) ? (ownt - o) : (ownt + o);
        bool ok = (t >= 0) && (t < NTILES);
        if (ok) {
            const float dx = fmaxf(0.f, fmaxf(sab[t*6+0] - wqmxx, wqmnx - sab[t*6+3]));
            const float dy = fmaxf(0.f, fmaxf(sab[t*6+1] - wqmxy, wqmny - sab[t*6+4]));
            const float dz = fmaxf(0.f, fmaxf(sab[t*6+2] - wqmxz, wqmnz - sab[t*6+5]));
            float lb = dx * dx;
            lb = fmaf(dy, dy, lb);
            lb = fmaf(dz, dz, lb);
            ok = (lb - 1e-3f) <= wmax;   // margin >> fp32 chain error
        }
        const unsigned long long mk = __ballot(ok);
        if (ok) {
            const int idx = nsurv + (int)__popcll(mk & ((1ull << lane) - 1ull));
            slist[wave][idx] = (unsigned char)t;
        }
        nsurv += (int)__popcll(mk);
    }

    // ---- scan survivors with ping-pong register prefetch ----
    float4 A0, A1, B0, B1;
    {
        const int ta = (0 < nsurv) ? (int)slist[wave][0] : ownt;
        A0 = cd[ta * TILE + lane]; A1 = cd[ta * TILE + 64 + lane];
        const int tb = (1 < nsurv) ? (int)slist[wave][1] : ownt;
        B0 = cd[tb * TILE + lane]; B1 = cd[tb * TILE + 64 + lane];
    }
    int s = 0;
    while (s < nsurv) {
        const int tnA = (s + 2 < nsurv) ? (int)slist[wave][s + 2] : ownt;
        PROCESS_BATCH(A0, false);
        PROCESS_BATCH(A1, false);
        A0 = cd[tnA * TILE + lane]; A1 = cd[tnA * TILE + 64 + lane];
        ++s;
        if (s >= nsurv) break;
        const int tnB = (s + 2 < nsurv) ? (int)slist[wave][s + 2] : ownt;
        PROCESS_BATCH(B0, false);
        PROCESS_BATCH(B1, false);
        B0 = cd[tnB * TILE + lane]; B1 = cd[tnB * TILE + 64 + lane];
        ++s;
    }

    // Rank 0 (lex-smallest: self or -1ulp near-twin) dropped positionally.
    // Ranks 1..10 -> feature columns 0..9. li holds ORIGINAL indices.
    float fv = -FLT_MAX;
    if (inlist && lrank >= 1)
        fv = feats[(size_t)li * C_FEAT + (lrank - 1)];
    #pragma unroll
    for (int off = 1; off < 16; off <<= 1)
        fv = fmaxf(fv, __shfl_xor(fv, off));

    #pragma unroll
    for (int q = 0; q < WQ; ++q) {
        const float M   = __shfl(fv, q * 16);
        const int   row = qor[q];
        const float v   = feats[(size_t)row * C_FEAT + lane];
        outb[(size_t)row * (2 * C_FEAT) + lane]          = v;
        outb[(size_t)row * (2 * C_FEAT) + C_FEAT + lane] = M - v;
    }
}

extern "C" void kernel_launch(void* const* d_in, const int* in_sizes, int n_in,
                              void* d_out, int out_size, void* d_ws, size_t ws_size,
                              hipStream_t stream) {
    const float* src_f = (const float*)d_in[0];
    const float* tgt_f = (const float*)d_in[1];
    const float* src_c = (const float*)d_in[2];
    const float* tgt_c = (const float*)d_in[3];
    float* out = (float*)d_out;

    char* ws = (char*)d_ws;
    float4* cand = (float4*)(ws + WS_CAND);
    int*    hist = (int*)   (ws + WS_HIST);
    int*    cptr = (int*)   (ws + WS_PTR);
    float*  aabb = (float*) (ws + WS_AABB);

    hipMemsetAsync(hist, 0, 2 * NCELLS * sizeof(int), stream);
    hipLaunchKernelGGL(hist_kernel, dim3(2 * N_PTS / 256), dim3(256), 0, stream,
                       src_c, tgt_c, hist);
    hipLaunchKernelGGL(scan_kernel, dim3(2), dim3(1024), 0, stream, hist, cptr);
    hipLaunchKernelGGL(scatter_kernel, dim3(2 * N_PTS / 256), dim3(256), 0, stream,
                       src_c, tgt_c, cptr, cand);
    hipLaunchKernelGGL(aabb_kernel, dim3(2 * NTILES), dim3(64), 0, stream,
                       cand, aabb);
    hipLaunchKernelGGL(knn_pool_kernel, dim3(2 * (N_PTS / QPB)), dim3(NTHREADS),
                       0, stream, src_f, tgt_f, cand, aabb, out);
}

// Round 10
// 236.026 us; speedup vs baseline: 1.5731x; 1.0166x over previous
//
#include <hip/hip_runtime.h>
#include <cfloat>
#include <math.h>

// Exact-replication KNN (k=10, +self) + rank-column gather max-pool.
// NUMERICS FROZEN (R3 pass, absmax 0.0): fp32 chains
//   sq  = fma(z,z, fma(y,y, rn(x*x)))
//   dot = fma(z,z', fma(y,y', rn(x*x')))
//   d   = fma(dot, -2, rn(sq_i+sq_j))    [== rn(sum - rn(2*dot)), 2*dot exact]
// Selection order = jax top_k = ascending lexicographic (d, orig_idx) —
// proven order-independent in R8/R9 (absmax 0.0, nondeterministic scatter).
//
// Round 10: tail + overhead.
//  - Survivor entries carry their AABB lower bound packed with the tile id
//    ((lb_bits & ~0xFF) | tile; monotone for lb>=0, unpack rounds lb DOWN ->
//    conservative). Before processing each survivor, recheck lb against the
//    CURRENT wmax — worst tightens during the scan, so far tiles die mid-
//    flight (R9 processed them anyway; that was the 48%-busy tail).
//  - Prepass fused: hist+scan+scatter in ONE 2-block kernel with an LDS
//    histogram (no global hist, no memset) -> 3 dispatches total.
//  - slist is u32 now (R9's byte writes were the bank-conflict counter).

#define N_PTS    16384
#define C_FEAT   64
#define KK       11
#define NCELLS   4096                 // 16^3 Morton cells
#define TILE     128                  // sorted points per tile
#define NTILES   (N_PTS / TILE)       // 128
#define WQ       4
#define NWAVES   4
#define NTHREADS (NWAVES * 64)
#define QPB      (NWAVES * WQ)        // 16 queries per block

// d_ws layout (bytes)
#define WS_CAND  0                          // float4[2][N_PTS]   512 KB
#define WS_AABB  (WS_CAND + 2*N_PTS*16)     // float[2][NTILES][6]

__device__ __forceinline__ int cell_of(float x, float y, float z) {
    int cx = (int)floorf((x + 4.5f) * (16.0f / 9.0f));
    int cy = (int)floorf((y + 4.5f) * (16.0f / 9.0f));
    int cz = (int)floorf((z + 4.5f) * (16.0f / 9.0f));
    cx = min(15, max(0, cx));
    cy = min(15, max(0, cy));
    cz = min(15, max(0, cz));
    int m = 0;
    #pragma unroll
    for (int b = 0; b < 4; ++b)
        m |= (((cx >> b) & 1) << (3 * b)) |
             (((cy >> b) & 1) << (3 * b + 1)) |
             (((cz >> b) & 1) << (3 * b + 2));
    return m;
}

// Fused hist + scan + scatter. One block per instance, 1024 threads.
__global__ __launch_bounds__(1024) void sort_kernel(
    const float* __restrict__ src_c, const float* __restrict__ tgt_c,
    float4* __restrict__ cand)
{
    const int inst = blockIdx.x;
    const float* __restrict__ coords = inst ? tgt_c : src_c;
    float4* __restrict__ cb = cand + inst * N_PTS;

    __shared__ int hist[NCELLS];   // becomes running write-pointer after scan
    __shared__ int sd[1024];
    const int t = threadIdx.x;

    for (int i = t; i < NCELLS; i += 1024) hist[i] = 0;
    __syncthreads();

    int mycell[16];
    #pragma unroll
    for (int j = 0; j < 16; ++j) {
        const int p = j * 1024 + t;
        const float* c = coords + (size_t)p * 3;
        mycell[j] = cell_of(c[0], c[1], c[2]);
        atomicAdd(&hist[mycell[j]], 1);
    }
    __syncthreads();

    int v[4], ssum = 0;
    #pragma unroll
    for (int j = 0; j < 4; ++j) { v[j] = hist[t * 4 + j]; ssum += v[j]; }
    sd[t] = ssum;
    __syncthreads();
    for (int off = 1; off < 1024; off <<= 1) {
        const int x = (t >= off) ? sd[t - off] : 0;
        __syncthreads();
        sd[t] += x;
        __syncthreads();
    }
    int base = sd[t] - ssum;
    #pragma unroll
    for (int j = 0; j < 4; ++j) { hist[t * 4 + j] = base; base += v[j]; }
    __syncthreads();

    #pragma unroll
    for (int j = 0; j < 16; ++j) {
        const int p = j * 1024 + t;
        const float* c = coords + (size_t)p * 3;
        const int dst = atomicAdd(&hist[mycell[j]], 1);
        cb[dst] = make_float4(c[0], c[1], c[2], __int_as_float(p));
    }
}

__global__ void aabb_kernel(const float4* __restrict__ cand,
                            float* __restrict__ aabb) {
    const int it = blockIdx.x;                 // inst*NTILES + tile
    const int base = (it / NTILES) * N_PTS + (it % NTILES) * TILE;
    const int lane = threadIdx.x;              // 64 threads, 2 pts each
    float4 a = cand[base + lane], b = cand[base + 64 + lane];
    float mnx = fminf(a.x, b.x), mny = fminf(a.y, b.y), mnz = fminf(a.z, b.z);
    float mxx = fmaxf(a.x, b.x), mxy = fmaxf(a.y, b.y), mxz = fmaxf(a.z, b.z);
    #pragma unroll
    for (int off = 1; off < 64; off <<= 1) {
        mnx = fminf(mnx, __shfl_xor(mnx, off));
        mny = fminf(mny, __shfl_xor(mny, off));
        mnz = fminf(mnz, __shfl_xor(mnz, off));
        mxx = fmaxf(mxx, __shfl_xor(mxx, off));
        mxy = fmaxf(mxy, __shfl_xor(mxy, off));
        mxz = fmaxf(mxz, __shfl_xor(mxz, off));
    }
    if (lane == 0) {
        aabb[it * 6 + 0] = mnx; aabb[it * 6 + 1] = mny; aabb[it * 6 + 2] = mnz;
        aabb[it * 6 + 3] = mxx; aabb[it * 6 + 4] = mxy; aabb[it * 6 + 5] = mxz;
    }
}

// One 64-candidate batch vs the wave's 4 queries (proven in R8/R9).
#define PROCESS_BATCH(C, INIT)                                              \
  {                                                                         \
    const float cx = (C).x, cy = (C).y, cz = (C).z;                         \
    const int corig = __float_as_int((C).w);                                \
    const float csq = __fmaf_rn(cz, cz, __fmaf_rn(cy, cy,                   \
                                __fmul_rn(cx, cx)));                        \
    _Pragma("unroll")                                                       \
    for (int q = 0; q < WQ; ++q) {                                          \
      float dot = __fmul_rn(cx, qx[q]);                                     \
      dot = __fmaf_rn(cy, qy[q], dot);                                      \
      dot = __fmaf_rn(cz, qz[q], dot);                                      \
      const float sum = __fadd_rn(qsq[q], csq);                             \
      const float d = __fmaf_rn(dot, -2.0f, sum);                           \
      if (INIT) {                                                           \
        float t16 = d;                                                      \
        _Pragma("unroll")                                                   \
        for (int off = 1; off < 16; off <<= 1)                              \
          t16 = fmaxf(t16, __shfl_xor(t16, off));                           \
        worst[q] = __int_as_float(__builtin_amdgcn_readlane(                \
            __float_as_int(t16), q * 16));                                  \
      }                                                                     \
      unsigned long long m = __ballot(d <= worst[q]);                       \
      while (m) {                                                           \
        const int sl = (int)__builtin_ctzll(m);                             \
        m &= m - 1;                                                         \
        const float nd = __int_as_float(__builtin_amdgcn_readlane(          \
            __float_as_int(d), sl));                                        \
        if (nd <= worst[q]) {                                               \
          const int norig = __builtin_amdgcn_readlane(corig, sl);           \
          const float pld = __int_as_float(                                 \
              __builtin_amdgcn_ds_bpermute(upaddr, __float_as_int(ld)));    \
          const int pli = __builtin_amdgcn_ds_bpermute(upaddr, li);         \
          const bool gt = (ld > nd) || (ld == nd && li > norig);            \
          if (ingrp[q] && gt) {                                             \
            const bool pgt = (pld > nd) || (pld == nd && pli > norig);      \
            const bool fst = (lrank == 0) || (!pgt);                        \
            ld = fst ? nd : pld;                                            \
            li = fst ? norig : pli;                                         \
          }                                                                 \
          worst[q] = fminf(worst[q],                                        \
              __int_as_float(__builtin_amdgcn_readlane(                     \
                  __float_as_int(ld), q * 16 + (KK - 1))));                 \
        }                                                                   \
      }                                                                     \
    }                                                                       \
  }

#define WMAX4 fmaxf(fmaxf(worst[0], worst[1]), fmaxf(worst[2], worst[3]))

__global__ __launch_bounds__(NTHREADS) void knn_pool_kernel(
    const float* __restrict__ src_f, const float* __restrict__ tgt_f,
    const float4* __restrict__ cand, const float* __restrict__ aabb,
    float* __restrict__ out)
{
    const int inst = blockIdx.x & 1;
    const float* __restrict__ feats = inst ? tgt_f : src_f;
    float* __restrict__ outb = out + (size_t)inst * N_PTS * (2 * C_FEAT);
    const float4* __restrict__ cd = cand + inst * N_PTS;

    const int tid = threadIdx.x, wave = tid >> 6, lane = tid & 63;
    const int lq = lane >> 4, lrank = lane & 15;
    const bool inlist = (lrank < KK);
    const int upaddr = ((lane + 63) & 63) << 2;   // ds_bpermute: lane-1

    __shared__ float sab[NTILES * 6];                 // 3 KB
    __shared__ unsigned int slist[NWAVES][NTILES];    // packed (lb|tile), 2 KB
    for (int i = tid; i < NTILES * 6; i += NTHREADS)
        sab[i] = aabb[inst * NTILES * 6 + i];
    __syncthreads();

    const int q0 = (blockIdx.x >> 1) * QPB + wave * WQ;  // sorted row
    float qx[WQ], qy[WQ], qz[WQ], qsq[WQ];
    int qor[WQ]; bool ingrp[WQ]; float worst[WQ];
    float wqmnx = FLT_MAX, wqmny = FLT_MAX, wqmnz = FLT_MAX;
    float wqmxx = -FLT_MAX, wqmxy = -FLT_MAX, wqmxz = -FLT_MAX;
    #pragma unroll
    for (int q = 0; q < WQ; ++q) {
        const float4 c = cd[q0 + q];
        qx[q] = c.x; qy[q] = c.y; qz[q] = c.z;
        qor[q] = __float_as_int(c.w);
        qsq[q] = __fmaf_rn(c.z, c.z, __fmaf_rn(c.y, c.y, __fmul_rn(c.x, c.x)));
        ingrp[q] = inlist && (lq == q);
        worst[q] = FLT_MAX;
        wqmnx = fminf(wqmnx, c.x); wqmxx = fmaxf(wqmxx, c.x);
        wqmny = fminf(wqmny, c.y); wqmxy = fmaxf(wqmxy, c.y);
        wqmnz = fminf(wqmnz, c.z); wqmxz = fmaxf(wqmxz, c.z);
    }

    float ld = FLT_MAX;   // lane-distributed sorted list (lex (d, orig_idx))
    int   li = 0x7fffffff;

    const int ownt = q0 / TILE;   // tile containing the queries

    // ---- own tile first: worst init on batch 0, tighten through batch 1 --
    {
        const float4 c0 = cd[ownt * TILE + lane];
        const float4 c1 = cd[ownt * TILE + 64 + lane];
        PROCESS_BATCH(c0, true);
        PROCESS_BATCH(c1, false);
    }
    const float wmax0 = WMAX4;

    // ---- zigzag (near->far) survivor list, built in parallel ----
    // entry = (float_bits(lb) & ~0xFF) | tile  — lb>=0 so uint order == lb
    // order; unpacked lb rounds DOWN => recheck skip stays conservative.
    int nsurv = 0;
    #pragma unroll
    for (int g = 0; g < 4; ++g) {
        const int p = g * 64 + lane;
        const int o = (p >> 1) + 1;
        const int t = (p & 1) ? (ownt - o) : (ownt + o);
        bool ok = (t >= 0) && (t < NTILES);
        float lb = 0.0f;
        if (ok) {
            const float dx = fmaxf(0.f, fmaxf(sab[t*6+0] - wqmxx, wqmnx - sab[t*6+3]));
            const float dy = fmaxf(0.f, fmaxf(sab[t*6+1] - wqmxy, wqmny - sab[t*6+4]));
            const float dz = fmaxf(0.f, fmaxf(sab[t*6+2] - wqmxz, wqmnz - sab[t*6+5]));
            lb = dx * dx;
            lb = fmaf(dy, dy, lb);
            lb = fmaf(dz, dz, lb);
            ok = (lb - 1e-3f) <= wmax0;   // margin >> fp32 chain error
        }
        const unsigned long long mk = __ballot(ok);
        if (ok) {
            const int idx = nsurv + (int)__popcll(mk & ((1ull << lane) - 1ull));
            slist[wave][idx] = (__float_as_uint(lb) & 0xFFFFFF00u) | (unsigned)t;
        }
        nsurv += (int)__popcll(mk);
    }

    // ---- scan survivors: ping-pong prefetch + LIVE recheck vs current wmax
    float4 A0, A1, B0, B1;
    unsigned int uA = 0, uB = 0;
    {
        uA = (0 < nsurv) ? slist[wave][0] : (unsigned)ownt;
        const int ta = (int)(uA & 0xFFu);
        A0 = cd[ta * TILE + lane]; A1 = cd[ta * TILE + 64 + lane];
        uB = (1 < nsurv) ? slist[wave][1] : (unsigned)ownt;
        const int tb = (int)(uB & 0xFFu);
        B0 = cd[tb * TILE + lane]; B1 = cd[tb * TILE + 64 + lane];
    }
    int s = 0;
    while (s < nsurv) {
        {
            const unsigned int uN = (s + 2 < nsurv) ? slist[wave][s + 2]
                                                    : (unsigned)ownt;
            const int tn = (int)(uN & 0xFFu);
            if (__uint_as_float(uA & 0xFFFFFF00u) - 1e-3f <= WMAX4) {
                PROCESS_BATCH(A0, false);
                PROCESS_BATCH(A1, false);
            }
            uA = uN;
            A0 = cd[tn * TILE + lane]; A1 = cd[tn * TILE + 64 + lane];
            ++s;
            if (s >= nsurv) break;
        }
        {
            const unsigned int uN = (s + 2 < nsurv) ? slist[wave][s + 2]
                                                    : (unsigned)ownt;
            const int tn = (int)(uN & 0xFFu);
            if (__uint_as_float(uB & 0xFFFFFF00u) - 1e-3f <= WMAX4) {
                PROCESS_BATCH(B0, false);
                PROCESS_BATCH(B1, false);
            }
            uB = uN;
            B0 = cd[tn * TILE + lane]; B1 = cd[tn * TILE + 64 + lane];
            ++s;
        }
    }

    // Rank 0 (lex-smallest: self or -1ulp near-twin) dropped positionally.
    // Ranks 1..10 -> feature columns 0..9. li holds ORIGINAL indices.
    float fv = -FLT_MAX;
    if (inlist && lrank >= 1)
        fv = feats[(size_t)li * C_FEAT + (lrank - 1)];
    #pragma unroll
    for (int off = 1; off < 16; off <<= 1)
        fv = fmaxf(fv, __shfl_xor(fv, off));

    #pragma unroll
    for (int q = 0; q < WQ; ++q) {
        const float M   = __shfl(fv, q * 16);
        const int   row = qor[q];
        const float v   = feats[(size_t)row * C_FEAT + lane];
        outb[(size_t)row * (2 * C_FEAT) + lane]          = v;
        outb[(size_t)row * (2 * C_FEAT) + C_FEAT + lane] = M - v;
    }
}

extern "C" void kernel_launch(void* const* d_in, const int* in_sizes, int n_in,
                              void* d_out, int out_size, void* d_ws, size_t ws_size,
                              hipStream_t stream) {
    const float* src_f = (const float*)d_in[0];
    const float* tgt_f = (const float*)d_in[1];
    const float* src_c = (const float*)d_in[2];
    const float* tgt_c = (const float*)d_in[3];
    float* out = (float*)d_out;

    char* ws = (char*)d_ws;
    float4* cand = (float4*)(ws + WS_CAND);
    float*  aabb = (float*) (ws + WS_AABB);

    hipLaunchKernelGGL(sort_kernel, dim3(2), dim3(1024), 0, stream,
                       src_c, tgt_c, cand);
    hipLaunchKernelGGL(aabb_kernel, dim3(2 * NTILES), dim3(64), 0, stream,
                       cand, aabb);
    hipLaunchKernelGGL(knn_pool_kernel, dim3(2 * (N_PTS / QPB)), dim3(NTHREADS),
                       0, stream, src_f, tgt_f, cand, aabb, out);
}